// Round 13
// baseline (472.396 us; speedup 1.0000x reference)
//
#include <hip/hip_runtime.h>
#include <hip/hip_cooperative_groups.h>

namespace cg = cooperative_groups;

#define GDIM 38
#define GG   (GDIM * GDIM)          // 1444
#define TOTAL (GDIM * GDIM * GDIM)  // 54872
#define HALF  (TOTAL / 2)           // 27436
#define HWORDS (HALF / 2)           // 13718 packed u32 words per half
#define NSLICE 64                   // atom slices for histogram
#define BS 256
#define NBLK 512                    // 2 blocks/CU (LDS-limited) — co-resident

typedef float f32x4 __attribute__((ext_vector_type(4)));

// packed (disp+1) per k: dx | dy<<8 | dz<<16
__device__ __constant__ unsigned int c_dp[13] = {
    0x010100u, 0x010000u, 0x010001u, 0x010002u,
    0x000200u, 0x000201u, 0x000202u,
    0x000100u, 0x000101u, 0x000102u,
    0x000000u, 0x000001u, 0x000002u};

// translation-case table bit-packed: 5 bits/entry, 12 entries per u64 (no mem load)
__device__ __forceinline__ int case_of(int cidx) {
    constexpr unsigned long long W0 = 11ULL | (2ULL << 5) | (8ULL << 15) | (1ULL << 20)
        | (5ULL << 30) | (14ULL << 35) | (12ULL << 45) | (3ULL << 50);
    constexpr unsigned long long W1 = 9ULL | (6ULL << 15) | (15ULL << 20)
        | (13ULL << 30) | (4ULL << 35) | (10ULL << 45) | (17ULL << 50);
    constexpr unsigned long long W2 = 7ULL | (16ULL << 5);
    unsigned long long wv = cidx < 12 ? W0 : (cidx < 24 ? W1 : W2);
    int base = cidx < 12 ? 0 : (cidx < 24 ? 12 : 24);
    return (int)((wv >> (5 * (cidx - base))) & 31ULL);
}

__global__ __launch_bounds__(BS) void mega_kernel(
    const float* __restrict__ coords, const float* __restrict__ cell,
    float* __restrict__ out, unsigned int* __restrict__ parts,
    int* __restrict__ cnt, int* __restrict__ chunksum, int N)
{
    __shared__ unsigned int smem[HWORDS];    // 54.9 KB (union across phases)
    float* s = (float*)smem;
    cg::grid_group grid = cg::this_grid();

    const int tid = threadIdx.x, bid = blockIdx.x;
    const int w = tid >> 6, lane = tid & 63;
    const long long OFF1 = 3LL * N, OFF2 = 4LL * N, OFF3 = 17LL * N;

    // ================= Phase A: frac + flat + neighbors (R11 structure) ======
    const int ntiles = (N + BS - 1) / BS;
    for (int tile = bid; tile < ntiles; tile += NBLK) {
        const long long wbase = (long long)tile * BS + 64 * w;
        if (wbase < N) {
            float* sc  = s + 192 * w;
            float* snf = s + 768 + 832 * w;
            float* snc = s + 4096 + 832 * w;
            const bool fullwave = (wbase + 64 <= N);
            const int nval = fullwave ? 64 : (int)(N - wbase);

            if (fullwave) {
                const f32x4* src = (const f32x4*)(coords + wbase * 3);
                if (lane < 48) ((f32x4*)sc)[lane] = src[lane];
            } else {
                const float* src = coords + wbase * 3;
                for (int j = lane; j < nval * 3; j += 64) sc[j] = src[j];
            }

            if (lane < nval) {
                int v[3];
#pragma unroll
                for (int a = 0; a < 3; ++a) {
                    float d = cell[4 * a];           // diagonal
                    float f = sc[3 * lane + a] / d;  // IEEE divide, matches jnp
                    f = f - floorf(f);
                    if (f >= 1.0f) f -= 1.0f;
                    if (f < 0.0f)  f += 1.0f;
                    sc[3 * lane + a] = f;            // frac in place
                    v[a] = (int)floorf(f * (float)GDIM);
                }
                int flat = v[0] * GG + v[1] * GDIM + v[2];
                out[OFF1 + wbase + lane] = (float)flat;   // plain store (re-read in B)

#pragma unroll
                for (int k = 0; k < 13; ++k) {
                    const unsigned int dp = c_dp[k];
                    const int n0 = v[0] + (int)(dp & 0xFFu);
                    const int n1 = v[1] + (int)((dp >> 8) & 0xFFu);
                    const int n2 = v[2] + (int)((dp >> 16) & 0xFFu);
                    const int cat0 = (n0 == 0) ? 0 : ((n0 == GDIM + 1) ? 2 : 1);
                    const int cat1 = (n1 == 0) ? 0 : ((n1 == GDIM + 1) ? 2 : 1);
                    const int cat2 = (n2 == 0) ? 0 : ((n2 == GDIM + 1) ? 2 : 1);
                    const int m0 = (n0 == 0) ? (GDIM - 1) : ((n0 == GDIM + 1) ? 0 : n0 - 1);
                    const int m1 = (n1 == 0) ? (GDIM - 1) : ((n1 == GDIM + 1) ? 0 : n1 - 1);
                    const int m2 = (n2 == 0) ? (GDIM - 1) : ((n2 == GDIM + 1) ? 0 : n2 - 1);
                    snf[13 * lane + k] = (float)(m0 * GG + m1 * GDIM + m2);
                    snc[13 * lane + k] = (float)case_of(cat0 * 9 + cat1 * 3 + cat2);
                }
            }

            if (fullwave) {
                f32x4* dfr = (f32x4*)(out + wbase * 3);
                if (lane < 48) __builtin_nontemporal_store(((f32x4*)sc)[lane], &dfr[lane]);
                f32x4* dnf = (f32x4*)(out + OFF2 + wbase * 13);
                f32x4* dnc = (f32x4*)(out + OFF3 + wbase * 13);
#pragma unroll
                for (int j = lane; j < 208; j += 64) {
                    __builtin_nontemporal_store(((f32x4*)snf)[j], &dnf[j]);
                    __builtin_nontemporal_store(((f32x4*)snc)[j], &dnc[j]);
                }
            } else {
                float* dfr = out + wbase * 3;
                for (int j = lane; j < nval * 3; j += 64)
                    __builtin_nontemporal_store(sc[j], &dfr[j]);
                float* dnf = out + OFF2 + wbase * 13;
                float* dnc = out + OFF3 + wbase * 13;
                for (int j = lane; j < nval * 13; j += 64) {
                    __builtin_nontemporal_store(snf[j], &dnf[j]);
                    __builtin_nontemporal_store(snc[j], &dnc[j]);
                }
            }
        }
    }
    __threadfence();
    grid.sync();

    // ================= Phase B: LDS-packed-u16 histogram (blocks 0..127) =====
    if (bid < 2 * NSLICE) {
        const int half = bid & 1, slice = bid >> 1, lo = half * HALF;
        for (int j = tid; j < HWORDS; j += BS) smem[j] = 0u;
        __syncthreads();
        const float* flatf = out + OFF1;
        for (long long i = (long long)slice * BS + tid; i < N;
             i += (long long)NSLICE * BS) {
            int flat = (int)flatf[i] - lo;
            if ((unsigned)flat < (unsigned)HALF)
                atomicAdd(&smem[flat >> 1], 1u << ((flat & 1) * 16));
        }
        __syncthreads();
        unsigned int* dst = parts + (long long)bid * HWORDS;
        for (int j = tid; j < HWORDS; j += BS) dst[j] = smem[j];
    }
    __threadfence();
    grid.sync();

    // ================= Phase C: reduce partials -> cnt =======================
    {
        const int task = bid * BS + tid;        // [0, 131072)
        if (task < 2 * HWORDS) {
            const int j = task >> 1, half = task & 1;
            unsigned int sum = 0;
#pragma unroll 8
            for (int ss = 0; ss < NSLICE; ++ss)
                sum += parts[(long long)(2 * ss + half) * HWORDS + j];
            const int b = half * HALF + 2 * j;
            cnt[b]     = (int)(sum & 0xFFFFu);
            cnt[b + 1] = (int)(sum >> 16);
        }
    }
    __threadfence();
    grid.sync();

    // ================= Phase D1: per-chunk sums ==============================
    const int NCHUNK = (TOTAL + BS - 1) / BS;   // 215
    int* ilds = (int*)smem;
    if (bid < NCHUNK) {
        const int idx = bid * BS + tid;
        const int c = (idx < TOTAL) ? cnt[idx] : 0;
        ilds[tid] = c;
        __syncthreads();
        for (int off = 128; off > 0; off >>= 1) {
            if (tid < off) ilds[tid] += ilds[tid + off];
            __syncthreads();
        }
        if (tid == 0) chunksum[bid] = ilds[0];
    }
    __threadfence();
    grid.sync();

    // ================= Phase D2: scan + count/cumcount outputs ===============
    if (bid < NCHUNK) {
        float* countf = out + 30LL * N;
        float* cumf   = countf + TOTAL;
        const int idx = bid * BS + tid;
        const int c = (idx < TOTAL) ? cnt[idx] : 0;

        ilds[tid] = (tid < bid) ? chunksum[tid] : 0;   // NCHUNK-1 <= 214 < 256
        __syncthreads();
        for (int off = 128; off > 0; off >>= 1) {
            if (tid < off) ilds[tid] += ilds[tid + off];
            __syncthreads();
        }
        const int blockpre = ilds[0];
        __syncthreads();

        ilds[tid] = c;                                  // Hillis–Steele inclusive
        __syncthreads();
        for (int off = 1; off < BS; off <<= 1) {
            int vp = (tid >= off) ? ilds[tid - off] : 0;
            __syncthreads();
            ilds[tid] += vp;
            __syncthreads();
        }
        const int exc = ilds[tid] - c;

        if (idx < TOTAL) {
            countf[idx] = (float)c;
            cumf[idx]   = (float)(blockpre + exc);
        }
    }
}

extern "C" void kernel_launch(void* const* d_in, const int* in_sizes, int n_in,
                              void* d_out, int out_size, void* d_ws, size_t ws_size,
                              hipStream_t stream)
{
    const float* coords = (const float*)d_in[0];
    const float* cell   = (const float*)d_in[1];
    float* out = (float*)d_out;
    unsigned int* parts = (unsigned int*)d_ws;            // 128*HWORDS u32 = 7 MB
    int* cnt = (int*)(parts + 2LL * NSLICE * HWORDS);
    int* chunksum = cnt + TOTAL;

    int N = (int)((out_size - 2 * TOTAL) / 30);           // out_size = 30N + 2*TOTAL

    void* args[] = {(void*)&coords, (void*)&cell, (void*)&out,
                    (void*)&parts, (void*)&cnt, (void*)&chunksum, (void*)&N};
    hipLaunchCooperativeKernel((void*)mega_kernel, dim3(NBLK), dim3(BS),
                               args, 0, stream);
}